// Round 1
// baseline (76.696 us; speedup 1.0000x reference)
//
#include <hip/hip_runtime.h>

// MultiScaleGraphConstruction: out[s,b,i,j] = dist(b,i,j) if MIN_DIST < dist < r_s else 0
// Bit-exact replication of the numpy/jax reference arithmetic:
//   diff = pos[b,i]-pos[b,j]; sq = ((dx*dx + dy*dy) + dz*dz)  [no FMA contraction!]
//   dist = sqrt_rn(max(sq, 1e-12f)); mask = (dist < r) & (dist > 1e-6f)

namespace {
constexpr int B = 8;
constexpr int N = 2048;                       // pos is (B, N, 3) f32
constexpr long long NN  = (long long)N * N;   // 4,194,304
constexpr long long BNN = (long long)B * NN;  // 33,554,432
}

__global__ __launch_bounds__(256) void msgc_kernel(const float* __restrict__ pos,
                                                   float* __restrict__ out) {
    const int bi = blockIdx.x;            // 0 .. B*N-1, one block per output row
    const int b  = bi >> 11;              // / 2048
    const int i  = bi & (N - 1);

    const float* __restrict__ pb = pos + (size_t)b * N * 3;
    const float xi = pb[3 * i + 0];
    const float yi = pb[3 * i + 1];
    const float zi = pb[3 * i + 2];

    const size_t rowbase = (size_t)b * NN + (size_t)i * N;
    float* __restrict__ o0 = out + rowbase;               // r = 3
    float* __restrict__ o1 = out + (size_t)BNN + rowbase; // r = 5
    float* __restrict__ o2 = out + (size_t)(2 * BNN) + rowbase; // r = 8

#pragma unroll
    for (int it = 0; it < 2; ++it) {
        const int j0 = (((int)threadIdx.x + (it << 8)) << 2);  // 4 consecutive j
        // 12 consecutive floats = pos[b, j0..j0+3, 0..2]; 48B offset -> 16B aligned
        const float4* p4 = reinterpret_cast<const float4*>(pb + (size_t)j0 * 3);
        const float4 a = p4[0];
        const float4 c = p4[1];
        const float4 e = p4[2];

        const float jx[4] = {a.x, a.w, c.z, e.y};
        const float jy[4] = {a.y, c.x, c.w, e.z};
        const float jz[4] = {a.z, c.y, e.x, e.w};

        float r0[4], r1[4], r2[4];
#pragma unroll
        for (int k = 0; k < 4; ++k) {
            const float dx = xi - jx[k];
            const float dy = yi - jy[k];
            const float dz = zi - jz[k];
            // Block FMA contraction: squares rounded individually, summed in
            // the reference's left-to-right order.
            const float s0 = __fmul_rn(dx, dx);
            const float s1 = __fmul_rn(dy, dy);
            const float s2 = __fmul_rn(dz, dz);
            const float sq = __fadd_rn(__fadd_rn(s0, s1), s2);
            const float dist = __fsqrt_rn(fmaxf(sq, 1e-12f));
            const bool gt = dist > 1e-6f;   // sqrt_rn(1e-12f) == 1e-6f exactly -> diagonal excluded
            r0[k] = (gt && dist < 3.0f) ? dist : 0.0f;
            r1[k] = (gt && dist < 5.0f) ? dist : 0.0f;
            r2[k] = (gt && dist < 8.0f) ? dist : 0.0f;
        }

        *reinterpret_cast<float4*>(o0 + j0) = make_float4(r0[0], r0[1], r0[2], r0[3]);
        *reinterpret_cast<float4*>(o1 + j0) = make_float4(r1[0], r1[1], r1[2], r1[3]);
        *reinterpret_cast<float4*>(o2 + j0) = make_float4(r2[0], r2[1], r2[2], r2[3]);
    }
}

extern "C" void kernel_launch(void* const* d_in, const int* in_sizes, int n_in,
                              void* d_out, int out_size, void* d_ws, size_t ws_size,
                              hipStream_t stream) {
    const float* pos = (const float*)d_in[0];
    float* out = (float*)d_out;
    msgc_kernel<<<dim3(B * N), dim3(256), 0, stream>>>(pos, out);
}

// Round 3
// 75.885 us; speedup vs baseline: 1.0107x; 1.0107x over previous
//
#include <hip/hip_runtime.h>

// MultiScaleGraphConstruction: out[s,b,i,j] = dist(b,i,j) if MIN_DIST < dist < r_s else 0
//
// Mask equivalence (bit-exact vs reference f32 arithmetic):
//   ref: dist = sqrt_rn(max(sq,1e-12)); mask = (dist < r) & (dist > 1e-6)
//   sqrt_rn is monotone + correctly rounded =>
//     dist < 3  <=>  sq < 9.0f            (sqrt_rn(nextbelow(9)) = 3-2^-22 < 3)
//     dist < 5  <=>  sq < nextbelow(25)   (sqrt_rn(nextbelow(25)) == 5 exactly!)
//     dist < 8  <=>  sq < 64.0f           (sqrt_rn(nextbelow(64)) = 8-2^-20 < 8)
//   dist > 1e-6 <=> sq > 0 (any flip in the ~1e-12 window errs by ~1e-6 << 0.16 thr)
// Value: v_sqrt_f32 approx (<=1 ulp, abs err ~1e-6 at dist<=8) is far inside the
// 0.16 absolute threshold; only the MASK needs exactness.
// sq computed in the reference order with no FMA contraction.

namespace {
constexpr int B = 8;
constexpr int N = 2048;                       // pos is (B, N, 3) f32
constexpr long long NN  = (long long)N * N;   // 4,194,304
constexpr long long BNN = (long long)B * NN;  // 33,554,432
typedef float vf4 __attribute__((ext_vector_type(4)));  // clang vector: OK for nontemporal builtin
}

__global__ __launch_bounds__(256) void msgc_kernel(const float* __restrict__ pos,
                                                   float* __restrict__ out) {
    const int bi = blockIdx.x;            // one block per output row (b,i)
    const int b  = bi >> 11;
    const int i  = bi & (N - 1);

    const float* __restrict__ pb = pos + (size_t)b * N * 3;
    const float xi = pb[3 * i + 0];
    const float yi = pb[3 * i + 1];
    const float zi = pb[3 * i + 2];

    const size_t rowbase = (size_t)b * NN + (size_t)i * N;
    float* __restrict__ o0 = out + rowbase;                      // r = 3
    float* __restrict__ o1 = out + (size_t)BNN + rowbase;        // r = 5
    float* __restrict__ o2 = out + (size_t)(2 * BNN) + rowbase;  // r = 8

    const float S5 = __uint_as_float(0x41C7FFFFu);  // nextbelow(25.0f)

#pragma unroll
    for (int it = 0; it < 2; ++it) {
        const int j0 = (((int)threadIdx.x + (it << 8)) << 2);  // 4 consecutive j
        const vf4* p4 = reinterpret_cast<const vf4*>(pb + (size_t)j0 * 3);
        const vf4 a = p4[0];
        const vf4 c = p4[1];
        const vf4 e = p4[2];

        const float jx[4] = {a.x, a.w, c.z, e.y};
        const float jy[4] = {a.y, c.x, c.w, e.z};
        const float jz[4] = {a.z, c.y, e.x, e.w};

        vf4 r0, r1, r2;
#pragma unroll
        for (int k = 0; k < 4; ++k) {
            const float dx = xi - jx[k];
            const float dy = yi - jy[k];
            const float dz = zi - jz[k];
            // No FMA contraction; reference summation order.
            const float s0 = __fmul_rn(dx, dx);
            const float s1 = __fmul_rn(dy, dy);
            const float s2 = __fmul_rn(dz, dz);
            const float sq = __fadd_rn(__fadd_rn(s0, s1), s2);
            const float dist = __builtin_amdgcn_sqrtf(sq);  // v_sqrt_f32, value-only
            const bool nz = sq > 0.0f;
            r0[k] = (nz && (sq < 9.0f))  ? dist : 0.0f;
            r1[k] = (nz && (sq < S5))    ? dist : 0.0f;
            r2[k] = (nz && (sq < 64.0f)) ? dist : 0.0f;
        }

        __builtin_nontemporal_store(r0, reinterpret_cast<vf4*>(o0 + j0));
        __builtin_nontemporal_store(r1, reinterpret_cast<vf4*>(o1 + j0));
        __builtin_nontemporal_store(r2, reinterpret_cast<vf4*>(o2 + j0));
    }
}

extern "C" void kernel_launch(void* const* d_in, const int* in_sizes, int n_in,
                              void* d_out, int out_size, void* d_ws, size_t ws_size,
                              hipStream_t stream) {
    const float* pos = (const float*)d_in[0];
    float* out = (float*)d_out;
    msgc_kernel<<<dim3(B * N), dim3(256), 0, stream>>>(pos, out);
}

// Round 4
// 70.605 us; speedup vs baseline: 1.0863x; 1.0748x over previous
//
#include <hip/hip_runtime.h>

// MultiScaleGraphConstruction: out[s,b,i,j] = dist(b,i,j) if MIN_DIST < dist < r_s else 0
//
// R4: one scale-plane per block (blockIdx.z = scale). Each block writes ONE
// contiguous 8KB row in ONE plane -> single-stream write pattern like the
// 6.9 TB/s fill kernel, instead of 3 simultaneous streams 2^27 B apart
// (DRAM channel/bank alias candidate). Distance compute is redundant 3x but
// VALU is ~13 us fully overlapped with stores.
//
// Mask equivalence (bit-exact vs reference f32 arithmetic):
//   ref: dist = sqrt_rn(max(sq,1e-12)); mask = (dist < r) & (dist > 1e-6)
//   sqrt_rn monotone + correctly rounded =>
//     dist < 3  <=>  sq < 9.0f
//     dist < 5  <=>  sq < nextbelow(25)  (sqrt_rn(nextbelow(25)) == 5 exactly)
//     dist < 8  <=>  sq < 64.0f
//   dist > 1e-6 <=> sq > 0. Value via v_sqrt_f32 (<=1 ulp << 0.16 threshold).
// sq computed in reference order, no FMA contraction.

namespace {
constexpr int B = 8;
constexpr int N = 2048;                       // pos is (B, N, 3) f32
constexpr long long NN  = (long long)N * N;   // 4,194,304
constexpr long long BNN = (long long)B * NN;  // 33,554,432
typedef float vf4 __attribute__((ext_vector_type(4)));
}

__global__ __launch_bounds__(256) void msgc_kernel(const float* __restrict__ pos,
                                                   float* __restrict__ out) {
    const int bi = blockIdx.x;            // one block per output row (b,i)
    const int b  = bi >> 11;
    const int i  = bi & (N - 1);
    const int s  = blockIdx.z;            // scale plane 0..2

    // squared-distance cutoff, bit-exact equivalent of (sqrt_rn(sq) < r)
    const float thr = (s == 0) ? 9.0f
                    : (s == 1) ? __uint_as_float(0x41C7FFFFu)   // nextbelow(25.0f)
                               : 64.0f;

    const float* __restrict__ pb = pos + (size_t)b * N * 3;
    const float xi = pb[3 * i + 0];
    const float yi = pb[3 * i + 1];
    const float zi = pb[3 * i + 2];

    float* __restrict__ orow = out + (size_t)s * BNN + (size_t)b * NN + (size_t)i * N;

#pragma unroll
    for (int it = 0; it < 2; ++it) {
        const int j0 = (((int)threadIdx.x + (it << 8)) << 2);  // 4 consecutive j
        const vf4* p4 = reinterpret_cast<const vf4*>(pb + (size_t)j0 * 3);
        const vf4 a = p4[0];
        const vf4 c = p4[1];
        const vf4 e = p4[2];

        const float jx[4] = {a.x, a.w, c.z, e.y};
        const float jy[4] = {a.y, c.x, c.w, e.z};
        const float jz[4] = {a.z, c.y, e.x, e.w};

        vf4 r;
#pragma unroll
        for (int k = 0; k < 4; ++k) {
            const float dx = xi - jx[k];
            const float dy = yi - jy[k];
            const float dz = zi - jz[k];
            // No FMA contraction; reference summation order.
            const float s0 = __fmul_rn(dx, dx);
            const float s1 = __fmul_rn(dy, dy);
            const float s2 = __fmul_rn(dz, dz);
            const float sq = __fadd_rn(__fadd_rn(s0, s1), s2);
            const float dist = __builtin_amdgcn_sqrtf(sq);  // value-only
            r[k] = ((sq > 0.0f) && (sq < thr)) ? dist : 0.0f;
        }

        __builtin_nontemporal_store(r, reinterpret_cast<vf4*>(orow + j0));
    }
}

extern "C" void kernel_launch(void* const* d_in, const int* in_sizes, int n_in,
                              void* d_out, int out_size, void* d_ws, size_t ws_size,
                              hipStream_t stream) {
    const float* pos = (const float*)d_in[0];
    float* out = (float*)d_out;
    msgc_kernel<<<dim3(B * N, 1, 3), dim3(256), 0, stream>>>(pos, out);
}